// Round 1
// baseline (139.584 us; speedup 1.0000x reference)
//
#include <hip/hip_runtime.h>
#include <hip/hip_bf16.h>
#include <stdint.h>

typedef __attribute__((ext_vector_type(8))) __bf16 bf16x8;
typedef __attribute__((ext_vector_type(16))) float floatx16;

#if __has_builtin(__builtin_amdgcn_exp2f)
#define EXP2F(x) __builtin_amdgcn_exp2f(x)
#else
#define EXP2F(x) exp2f(x)
#endif

#define GAS __attribute__((address_space(1)))
#define LAS __attribute__((address_space(3)))

// sqrt(2*log2(e)) = sqrt(2.885390081777927): baked into normalized vectors so
// dot(xb_i, xb_j) = 2*log2(e)*cos(i,j)  =>  sim = exp2(dot) = exp(cos/0.5)
#define SCALE_SQRT 1.69864359f

// ---------------- label dtype fixup (int64 hedge) ----------------
__global__ __launch_bounds__(256) void k_labels(const int* __restrict__ raw,
                                                int* __restrict__ lab, int N) {
  __shared__ int s_is64;
  if (threadIdx.x == 0) {
    int allzero = 1;
    for (int i = 0; i < 64; ++i)
      if (raw[2 * i + 1] != 0) { allzero = 0; break; }
    s_is64 = allzero;
  }
  __syncthreads();
  const int is64 = s_is64;
  for (int i = threadIdx.x; i < N; i += 256)
    lab[i] = is64 ? raw[2 * i] : raw[i];
}

// ---------------- normalize + scale + bf16 cast ----------------
__global__ __launch_bounds__(256) void k_normalize(const float* __restrict__ x,
                                                   ushort* __restrict__ xb, int N) {
  const int row = (blockIdx.x * 256 + threadIdx.x) >> 6;  // one wave per row
  const int lane = threadIdx.x & 63;
  if (row >= N) return;
  const float2 v = ((const float2*)(x + (size_t)row * 128))[lane];
  float ss = v.x * v.x + v.y * v.y;
#pragma unroll
  for (int m = 1; m < 64; m <<= 1) ss += __shfl_xor(ss, m, 64);
  const float rn = SCALE_SQRT / fmaxf(sqrtf(ss), 1e-12f);
  __hip_bfloat162 o;
  o.x = __float2bfloat16(v.x * rn);
  o.y = __float2bfloat16(v.y * rn);
  ((__hip_bfloat162*)xb)[row * 64 + lane] = o;
}

// ---------------- class histogram ----------------
__global__ __launch_bounds__(256) void k_hist(const int* __restrict__ lab,
                                              int* __restrict__ hist, int N) {
  __shared__ int h[64];
  if (threadIdx.x < 64) h[threadIdx.x] = 0;
  __syncthreads();
  for (int i = threadIdx.x; i < N; i += 256) atomicAdd(&h[lab[i] & 63], 1);
  __syncthreads();
  if (threadIdx.x < 64) hist[threadIdx.x] = h[threadIdx.x];
}

// ---------------- main: tiled x*x^T -> exp2 -> row pos/neg sums ----------------
// grid = (jchunks, N/128). Block 256 = 4 waves in 2x2, each wave 64x64 out.
// LDS tiles 128 rows x 256B, XOR-swizzled 16B blocks: kb_lds = kb_global ^ (row&7).
// Swizzle applied by permuting GLOBAL source addresses (global_load_lds writes
// lane-contiguous LDS, so the LDS side must stay linear).
__global__ __launch_bounds__(256, 2) void k_sim(const ushort* __restrict__ xb,
                                                const int* __restrict__ lab,
                                                float* __restrict__ negs,
                                                float* __restrict__ poss, int jpb) {
  __shared__ ushort ldsA[128 * 128];
  __shared__ ushort ldsB[128 * 128];
  const int tid = threadIdx.x;
  const int lane = tid & 63;
  const int wv = tid >> 6;
  const int wy = wv >> 1, wx = wv & 1;
  const int l31 = lane & 31, g2 = lane >> 5;
  const int l15 = lane & 15, g4 = lane >> 4;
  const int i0 = blockIdx.y * 128;

  // ---- stage A tile once (async, drained by the syncthreads in the j-loop) ----
#pragma unroll
  for (int it = 0; it < 8; ++it) {
    const int r0 = it * 16 + wv * 4;            // wave-uniform LDS row base
    const int lr = r0 + g4;
    const int kb = l15 ^ (lr & 7);              // source-permuted for swizzle
    const ushort* gp = xb + (size_t)(i0 + lr) * 128 + kb * 8;
    __builtin_amdgcn_global_load_lds((GAS void*)gp, (LAS void*)&ldsA[r0 * 128], 16, 0, 0);
  }

  // per-lane labels of the 32 rows this lane accumulates
  // C/D layout 32x32: col = lane&31, row = (reg&3) + 8*(reg>>2) + 4*(lane>>5)
  int li[32];
#pragma unroll
  for (int mi = 0; mi < 2; ++mi)
#pragma unroll
    for (int reg = 0; reg < 16; ++reg)
      li[mi * 16 + reg] = lab[i0 + wy * 64 + mi * 32 + (reg & 3) + 8 * (reg >> 2) + 4 * g2];

  float neg[32], pos[32];
#pragma unroll
  for (int t = 0; t < 32; ++t) { neg[t] = 0.0f; pos[t] = 0.0f; }

  const int jt0 = blockIdx.x * jpb;
  for (int t = 0; t < jpb; ++t) {
    const int j0 = (jt0 + t) * 128;
    __syncthreads();  // previous tile's ds_reads done -> safe to overwrite B
#pragma unroll
    for (int it = 0; it < 8; ++it) {
      const int r0 = it * 16 + wv * 4;
      const int lr = r0 + g4;
      const int kb = l15 ^ (lr & 7);
      const ushort* gp = xb + (size_t)(j0 + lr) * 128 + kb * 8;
      __builtin_amdgcn_global_load_lds((GAS void*)gp, (LAS void*)&ldsB[r0 * 128], 16, 0, 0);
    }
    const int lj0 = lab[j0 + wx * 64 + l31];
    const int lj1 = lab[j0 + wx * 64 + 32 + l31];
    __syncthreads();  // staging (A on first iter, B always) complete

    floatx16 acc[2][2];
#pragma unroll
    for (int mi = 0; mi < 2; ++mi)
#pragma unroll
      for (int ni = 0; ni < 2; ++ni) acc[mi][ni] = (floatx16)(0.0f);

#pragma unroll
    for (int kt = 0; kt < 8; ++kt) {
      bf16x8 af[2], bfr[2];
#pragma unroll
      for (int mi = 0; mi < 2; ++mi) {
        const int lr = wy * 64 + mi * 32 + l31;       // A: m = lane&31
        const int kb = (kt * 2 + g2) ^ (lr & 7);      // k-block, unswizzle
        af[mi] = *(const bf16x8*)&ldsA[lr * 128 + kb * 8];
      }
#pragma unroll
      for (int ni = 0; ni < 2; ++ni) {
        const int lr = wx * 64 + ni * 32 + l31;       // B(row-major n,k): n = lane&31
        const int kb = (kt * 2 + g2) ^ (lr & 7);
        bfr[ni] = *(const bf16x8*)&ldsB[lr * 128 + kb * 8];
      }
#pragma unroll
      for (int mi = 0; mi < 2; ++mi)
#pragma unroll
        for (int ni = 0; ni < 2; ++ni)
          acc[mi][ni] = __builtin_amdgcn_mfma_f32_32x32x16_bf16(af[mi], bfr[ni],
                                                                acc[mi][ni], 0, 0, 0);
    }

    // ---- epilogue: exp2, diag-skip, pos/neg row accumulation (registers only) ----
    const bool hasdiag = (j0 == i0);
    auto epi = [&](bool DG) {
#pragma unroll
      for (int mi = 0; mi < 2; ++mi) {
#pragma unroll
        for (int ni = 0; ni < 2; ++ni) {
          const int lj = ni ? lj1 : lj0;
#pragma unroll
          for (int reg = 0; reg < 16; ++reg) {
            float e = EXP2F(acc[mi][ni][reg]);
            if (DG) {
              const int irow = wy * 64 + mi * 32 + (reg & 3) + 8 * (reg >> 2) + 4 * g2;
              const int jcol = wx * 64 + ni * 32 + l31;
              if (irow == jcol) e = 0.0f;   // exclude self-similarity exactly
            }
            neg[mi * 16 + reg] += e;
            if (li[mi * 16 + reg] == lj) pos[mi * 16 + reg] += e;
          }
        }
      }
    };
    if (hasdiag) epi(true); else epi(false);
  }

  // ---- cross-lane reduce (sum over 32 columns) + one atomic per row ----
#pragma unroll
  for (int t = 0; t < 32; ++t) {
    float n = neg[t], p = pos[t];
#pragma unroll
    for (int m = 1; m < 32; m <<= 1) {
      n += __shfl_xor(n, m, 64);
      p += __shfl_xor(p, m, 64);
    }
    if (l31 == 0) {
      const int mi = t >> 4, reg = t & 15;
      const int i = i0 + wy * 64 + mi * 32 + (reg & 3) + 8 * (reg >> 2) + 4 * g2;
      atomicAdd(&negs[i], n);
      atomicAdd(&poss[i], p);
    }
  }
}

// ---------------- finalize: mean(-log(pos/cnt/neg)) ----------------
__global__ __launch_bounds__(256) void k_final(const float* __restrict__ negs,
                                               const float* __restrict__ poss,
                                               const int* __restrict__ lab,
                                               const int* __restrict__ hist,
                                               float* __restrict__ out, int N) {
  double s = 0.0;
  for (int i = threadIdx.x; i < N; i += 256) {
    const float cnt = (float)(hist[lab[i] & 63] - 1);
    s += (double)logf(negs[i] * cnt / poss[i]);
  }
#pragma unroll
  for (int m = 1; m < 64; m <<= 1) s += __shfl_xor(s, m, 64);
  __shared__ double wsum[4];
  if ((threadIdx.x & 63) == 0) wsum[threadIdx.x >> 6] = s;
  __syncthreads();
  if (threadIdx.x == 0)
    out[0] = (float)((wsum[0] + wsum[1] + wsum[2] + wsum[3]) / (double)N);
}

extern "C" void kernel_launch(void* const* d_in, const int* in_sizes, int n_in,
                              void* d_out, int out_size, void* d_ws, size_t ws_size,
                              hipStream_t stream) {
  const float* x = (const float*)d_in[0];
  const int* raw_label = (const int*)d_in[1];
  const int N = in_sizes[1];  // 8192
  char* ws = (char*)d_ws;
  ushort* xb = (ushort*)ws;                              // N*128 bf16 = 2 MB
  float* negs = (float*)(ws + (size_t)N * 128 * 2);      // N f32
  float* poss = negs + N;                                // N f32
  int* hist = (int*)(poss + N);                          // 64 ints
  int* lab = hist + 64;                                  // N ints
  float* out = (float*)d_out;

  hipMemsetAsync(negs, 0, (size_t)N * 2 * sizeof(float), stream);
  k_labels<<<dim3(1), dim3(256), 0, stream>>>(raw_label, lab, N);
  k_normalize<<<dim3(N / 4), dim3(256), 0, stream>>>(x, xb, N);
  k_hist<<<dim3(1), dim3(256), 0, stream>>>(lab, hist, N);

  const int itiles = N / 128;       // 64
  const int jchunks = 8;            // grid = 8 x 64 = 512 blocks (2/CU)
  const int jpb = itiles / jchunks; // 8 j-tiles per block
  k_sim<<<dim3(jchunks, itiles), dim3(256), 0, stream>>>(xb, lab, negs, poss, jpb);
  k_final<<<dim3(1), dim3(256), 0, stream>>>(negs, poss, lab, hist, out, N);
}